// Round 15
// baseline (178.022 us; speedup 1.0000x reference)
//
#include <hip/hip_runtime.h>

#define THREADS 512            // 8 waves/block; 2 blocks/CU; 4 waves/SIMD
#define ROWS    64             // rows per block (af[2][8]=64 AGPR per wave)
#define BINS    512
#define WORDS   128            // u8-packed: 4 bins per u32 word
#define LO      (-0.6f)
#define RANGE   (1.3f)

typedef short bf16x8 __attribute__((ext_vector_type(8)));
typedef float f32x4  __attribute__((ext_vector_type(4)));

// fp32 -> bf16 with round-to-nearest-even
__device__ __forceinline__ short f2bf(float f) {
    unsigned int u = __builtin_bit_cast(unsigned int, f);
    u = (u + 0x7FFFu + ((u >> 16) & 1u)) >> 16;
    return (short)u;
}

// cvt: fp32 -> bf16 into the FRAGMENT-BLOCKED layout (R13) so every MFMA
// operand load in scpp is one fully-coalesced dwordx4 at base+lane*16B.
__global__ __launch_bounds__(256)
void cvt_kernel(const float* __restrict__ X, short* __restrict__ Xb) {
    int i    = blockIdx.x * 256 + threadIdx.x;   // 0 .. 2^20-1
    int lane = i & 63;
    int ks   = (i >> 6) & 7;
    int g    = (i >> 9) & 255;
    int b    = i >> 17;
    int ln   = lane & 15, kq = lane >> 4;
    const float* src = X + ((size_t)(b * 4096 + g * 16 + ln) * 256 + ks * 32 + kq * 8);
    float4 v0 = ((const float4*)src)[0];
    float4 v1 = ((const float4*)src)[1];
    bf16x8 o;
    o[0] = f2bf(v0.x); o[1] = f2bf(v0.y); o[2] = f2bf(v0.z); o[3] = f2bf(v0.w);
    o[4] = f2bf(v1.x); o[5] = f2bf(v1.y); o[6] = f2bf(v1.z); o[7] = f2bf(v1.w);
    *(bf16x8*)(Xb + ((size_t)b << 20) + g * 4096 + ks * 512 + lane * 8) = o;
}

// R15: OCCUPANCY 2->4 waves/SIMD. R5's version of this shape failed on
// TA-scattered loads (R8 lesson); with the blocked layout that confound is
// gone. Per-wave: af[2][8]=64 AGPR + ~60 VGPR fits the 128 cap
// (launch_bounds(512,4)); R5 compiled this shape at VGPR_Count=52.
// VALU/DS/MFMA totals per CU unchanged; TLP doubles to cover phase gaps.
__global__ __launch_bounds__(THREADS, 4)
void scpp_kernel(const short* __restrict__ X, float* __restrict__ out) {
    extern __shared__ unsigned int hist[];   // 8192 words = 32 KB

    const int t    = threadIdx.x;
    const int wave = t >> 6;           // 0..7
    const int lane = t & 63;
    const int q    = lane >> 4;        // quad 0..3
    const int ln   = lane & 15;
    const int rg   = wave & 1;         // row-group: rows m0 + rg*32 .. +31
    const int cg   = wave >> 1;        // col-group: cols nt*64 + cg*16 .. +15
    const int bid  = blockIdx.x;       // 0..511 -> 2 blocks/CU, zero tail
    const int batch = bid & 7;         // XCD-batch pinning
    const int m0    = (bid >> 3) * ROWS;
    const short* Xb = X + ((size_t)batch << 20);

    // zero histograms: 8192 words / 512 threads
    #pragma unroll
    for (int i = 0; i < (ROWS * WORDS) / THREADS; ++i)
        hist[t + THREADS * i] = 0u;

    // A fragments: 2 strips of 16 rows; coalesced fragment loads; AGPR-resident.
    bf16x8 af[2][8];
    {
        #pragma unroll
        for (int s = 0; s < 2; ++s) {
            const short* ap = Xb + (size_t)((m0 >> 4) + rg * 2 + s) * 4096 + lane * 8;
            #pragma unroll
            for (int ks = 0; ks < 8; ++ks)
                af[s][ks] = *(const bf16x8*)(ap + ks * 512);
        }
        #pragma unroll
        for (int s = 0; s < 2; ++s)
            #pragma unroll
            for (int ks = 0; ks < 8; ++ks)
                asm volatile("" : "+v"(af[s][ks]));   // opaque: blocks remat
    }
    __syncthreads();   // hist zeros visible before atomics

    // bin transform: b = (v/256 - LO) * BINS/RANGE == v*scale + off
    const float scale = ((float)BINS / RANGE) / 256.0f;
    const float off   = -LO * ((float)BINS / RANGE);

    // loop-invariant per-strip histogram row pointer + bank swizzle
    // (lane ln owns row rg*32 + s*16 + ln via the swapped-operand MFMA)
    unsigned int* Hrow[2];
    unsigned      swzr[2];
    #pragma unroll
    for (int s = 0; s < 2; ++s) {
        int row = rg * 32 + s * 16 + ln;
        Hrow[s] = &hist[row * WORDS];
        swzr[s] = (unsigned)((row * 9) & 31);
    }

    // B fragment base for tile nt (coalesced: base + lane*16B)
    auto bptr = [&](int nt) {
        return Xb + (size_t)(nt * 4 + cg) * 4096 + lane * 8;
    };
    auto load4 = [&](bf16x8* d, const short* p, int ks0) {
        #pragma unroll
        for (int j = 0; j < 4; ++j)
            d[j] = *(const bf16x8*)(p + (ks0 + j) * 512);
    };
    auto mfmaH = [&](f32x4* acc, const bf16x8* bx, int ks0) {
        __builtin_amdgcn_s_setprio(1);
        #pragma unroll
        for (int j = 0; j < 4; ++j)
            #pragma unroll
            for (int s = 0; s < 2; ++s)   // swapped: bb as A, af as B -> D^T
                acc[s] = __builtin_amdgcn_mfma_f32_16x16x32_bf16(bx[j], af[s][ks0 + j], acc[s], 0, 0, 0);
        __builtin_amdgcn_s_setprio(0);
    };

    // K-loop: half-buffer lookahead (32 VGPR of B state; R6 pattern).
    bf16x8 bbA[4], bbB[4];
    load4(bbA, bptr(0), 0);
    for (int nt = 0; nt < 64; ++nt) {
        f32x4 acc[2];
        #pragma unroll
        for (int s = 0; s < 2; ++s) acc[s] = f32x4{0.f, 0.f, 0.f, 0.f};

        load4(bbB, bptr(nt), 4);         // second half of current tile
        mfmaH(acc, bbA, 0);
        if (nt + 1 < 64) load4(bbA, bptr(nt + 1), 0);   // first half of next
        mfmaH(acc, bbB, 4);

        // bins: 8 elements (2 strips x 4 regs), row = rg*32+s*16+ln per lane
        #pragma unroll
        for (int s = 0; s < 2; ++s)
            #pragma unroll
            for (int reg = 0; reg < 4; ++reg) {
                int b  = (int)__builtin_amdgcn_fmed3f(
                             acc[s][reg] * scale + off, 0.0f, 511.0f);
                int pw = (b >> 2) ^ swzr[s];
                atomicAdd(&Hrow[s][pw], 1u << ((b & 3) << 3));
            }
    }
    __syncthreads();   // all waves' atomics visible

    // epilogue, in-register per wave: rows 8w .. 8w+7 (u8 unpack)
    const float binw = RANGE / (float)BINS;
    #pragma unroll
    for (int rr = 0; rr < 8; ++rr) {
        const int r = wave * 8 + rr;
        const unsigned int msk = (unsigned int)(r * 9) & 31u;
        const unsigned int* H = &hist[r * WORDS];
        // lane L holds logical words 2L..2L+1 = bins 8L..8L+7 (un-swizzle)
        int cnt[8];
        #pragma unroll
        for (int i2 = 0; i2 < 2; ++i2) {
            unsigned int wd = H[(unsigned int)(2 * lane + i2) ^ msk];
            cnt[4 * i2 + 0] = (int)(wd & 0xFFu);
            cnt[4 * i2 + 1] = (int)((wd >> 8)  & 0xFFu);
            cnt[4 * i2 + 2] = (int)((wd >> 16) & 0xFFu);
            cnt[4 * i2 + 3] = (int)((wd >> 24) & 0xFFu);
        }
        int local = 0;
        #pragma unroll
        for (int u = 0; u < 8; ++u) local += cnt[u];
        // suffix-sum over lanes
        int suf = local;
        #pragma unroll
        for (int o2 = 1; o2 < 64; o2 <<= 1) {
            int o = __shfl_down(suf, o2, 64);
            if (lane + o2 < 64) suf += o;
        }
        int run = suf - local;
        int s[8];                       // s[u] = S[8*lane+u] = #values >= edge
        #pragma unroll
        for (int u = 7; u >= 0; --u) { run += cnt[u]; s[u] = run; }

        // answer 256 queries for this row: lane handles i = qq*64 + lane
        #pragma unroll
        for (int qq = 0; qq < 4; ++qq) {
            int i = qq * 64 + lane;
            float rv = 1.0f + (float)i * (4094.0f / 255.0f);
            int k = (int)rintf(rv) + 1;   // k-th largest, k in [2, 4096]
            int Lo = 0;
            #pragma unroll
            for (int st = 32; st >= 1; st >>= 1) {
                int cand = Lo + st;       // always <= 63
                int v = __shfl(s[0], cand, 64);
                if (v >= k) Lo = cand;
            }
            int j8 = 0;
            #pragma unroll
            for (int u = 0; u < 8; ++u) {
                int v = __shfl(s[u], Lo, 64);
                j8 += (v >= k) ? 1 : 0;
            }
            int j = 8 * Lo + j8 - 1;
            out[(size_t)(batch * 4096 + m0 + r) * 256 + i] = LO + ((float)j + 0.5f) * binw;
        }
    }
}

extern "C" void kernel_launch(void* const* d_in, const int* in_sizes, int n_in,
                              void* d_out, int out_size, void* d_ws, size_t ws_size,
                              hipStream_t stream) {
    static int attr_set = 0;
    if (!attr_set) {   // one-time, host-side, not a stream op (capture-safe)
        (void)hipFuncSetAttribute((const void*)scpp_kernel,
                                  hipFuncAttributeMaxDynamicSharedMemorySize, 32768);
        attr_set = 1;
    }
    const float* x = (const float*)d_in[0];
    float* out = (float*)d_out;
    short* xb = (short*)d_ws;                              // 16 MB blocked bf16
    hipLaunchKernelGGL(cvt_kernel, dim3(4096), dim3(256), 0, stream, x, xb);
    hipLaunchKernelGGL(scpp_kernel, dim3(512), dim3(THREADS), 32768, stream, xb, out);
}

// Round 16
// 174.788 us; speedup vs baseline: 1.0185x; 1.0185x over previous
//
#include <hip/hip_runtime.h>

#define THREADS 512            // 8 waves/block; 1 block/CU (128 KB u32 hist)
#define ROWS    64             // rows per block
#define BINS    512
#define LO      (-0.6f)
#define RANGE   (1.3f)
// pre-scale: inputs x sqrt(BINS/(RANGE*256)) so MFMA output is in bin units
#define SQS     1.24034735f
#define OFF     236.3076923f   // -LO * BINS / RANGE

typedef short bf16x8 __attribute__((ext_vector_type(8)));
typedef float f32x4  __attribute__((ext_vector_type(4)));

// fp32 -> bf16 with round-to-nearest-even
__device__ __forceinline__ short f2bf(float f) {
    unsigned int u = __builtin_bit_cast(unsigned int, f);
    u = (u + 0x7FFFu + ((u >> 16) & 1u)) >> 16;
    return (short)u;
}

// cvt: fp32 -> PRE-SCALED bf16 in the fragment-blocked layout (R13), so the
// MFMA accumulator lands directly in bin units (saves 1 VALU/element in scpp).
__global__ __launch_bounds__(256)
void cvt_kernel(const float* __restrict__ X, short* __restrict__ Xb) {
    int i    = blockIdx.x * 256 + threadIdx.x;   // 0 .. 2^20-1
    int lane = i & 63;
    int ks   = (i >> 6) & 7;
    int g    = (i >> 9) & 255;
    int b    = i >> 17;
    int ln   = lane & 15, kq = lane >> 4;
    const float* src = X + ((size_t)(b * 4096 + g * 16 + ln) * 256 + ks * 32 + kq * 8);
    float4 v0 = ((const float4*)src)[0];
    float4 v1 = ((const float4*)src)[1];
    bf16x8 o;
    o[0] = f2bf(v0.x * SQS); o[1] = f2bf(v0.y * SQS);
    o[2] = f2bf(v0.z * SQS); o[3] = f2bf(v0.w * SQS);
    o[4] = f2bf(v1.x * SQS); o[5] = f2bf(v1.y * SQS);
    o[6] = f2bf(v1.z * SQS); o[7] = f2bf(v1.w * SQS);
    *(bf16x8*)(Xb + ((size_t)b << 20) + g * 4096 + ks * 512 + lane * 8) = o;
}

// R16: MINIMAL per-element work. R13-R15 proved schedule x4 and occupancy x2
// are both null while VALUBusy (51%) is the top pipe -> cut the bin chain:
//  - acc init = OFF + pre-scaled inputs  => no fmac per element
//  - u32 hist (1 bin/word, 128 KB)       => increment is constant 1u
//  - no bank swizzle (b mod 32 is already ~uniform for Gaussian data)
// Per element: fmed3, cvt_i32, lshl_add, ds_add -- 3 VALU + 1 DS (was 9+1).
__global__ __launch_bounds__(THREADS, 2)   // 8 waves = 2/SIMD; cap 256
void scpp_kernel(const short* __restrict__ X, float* __restrict__ out) {
    extern __shared__ unsigned int hist[];   // 64 rows x 512 bins = 32768 words

    const int t    = threadIdx.x;
    const int wave = t >> 6;           // 0..7
    const int lane = t & 63;
    const int ln   = lane & 15;
    const int rg   = wave & 1;         // row-group: rows m0 + rg*32 .. +31
    const int cg   = wave >> 1;        // col-group: cols nt*64 + cg*16 .. +15
    const int bid  = blockIdx.x;       // 0..511
    const int batch = bid & 7;         // XCD-batch pinning
    const int m0    = (bid >> 3) * ROWS;
    const short* Xb = X + ((size_t)batch << 20);

    // zero histograms: 8192 uint4 / 512 threads = 16 each
    #pragma unroll
    for (int i = 0; i < 16; ++i)
        ((uint4*)hist)[t + THREADS * i] = uint4{0u, 0u, 0u, 0u};

    // A fragments: 2 strips of 16 rows; coalesced fragment loads.
    bf16x8 af[2][8];
    {
        #pragma unroll
        for (int s = 0; s < 2; ++s) {
            const short* ap = Xb + (size_t)((m0 >> 4) + rg * 2 + s) * 4096 + lane * 8;
            #pragma unroll
            for (int ks = 0; ks < 8; ++ks)
                af[s][ks] = *(const bf16x8*)(ap + ks * 512);
        }
        #pragma unroll
        for (int s = 0; s < 2; ++s)
            #pragma unroll
            for (int ks = 0; ks < 8; ++ks)
                asm volatile("" : "+v"(af[s][ks]));   // opaque: blocks remat
    }
    __syncthreads();   // hist zeros visible before atomics

    // loop-invariant per-strip histogram row base
    // (lane ln owns row rg*32 + s*16 + ln via the swapped-operand MFMA)
    unsigned int* Hrow[2];
    #pragma unroll
    for (int s = 0; s < 2; ++s)
        Hrow[s] = &hist[(rg * 32 + s * 16 + ln) * BINS];

    // B fragment base for tile nt (coalesced: base + lane*16B)
    auto bptr = [&](int nt) {
        return Xb + (size_t)(nt * 4 + cg) * 4096 + lane * 8;
    };
    auto load4 = [&](bf16x8* d, const short* p, int ks0) {
        #pragma unroll
        for (int j = 0; j < 4; ++j)
            d[j] = *(const bf16x8*)(p + (ks0 + j) * 512);
    };
    auto mfmaH = [&](f32x4* acc, const bf16x8* bx, int ks0) {
        __builtin_amdgcn_s_setprio(1);
        #pragma unroll
        for (int j = 0; j < 4; ++j)
            #pragma unroll
            for (int s = 0; s < 2; ++s)   // swapped: bb as A, af as B -> D^T
                acc[s] = __builtin_amdgcn_mfma_f32_16x16x32_bf16(bx[j], af[s][ks0 + j], acc[s], 0, 0, 0);
        __builtin_amdgcn_s_setprio(0);
    };

    // K-loop: half-buffer lookahead; minimal bins.
    bf16x8 bbA[4], bbB[4];
    load4(bbA, bptr(0), 0);
    for (int nt = 0; nt < 64; ++nt) {
        f32x4 acc[2];
        #pragma unroll
        for (int s = 0; s < 2; ++s)
            acc[s] = f32x4{OFF, OFF, OFF, OFF};   // acc already in bin units

        load4(bbB, bptr(nt), 4);         // second half of current tile
        mfmaH(acc, bbA, 0);
        if (nt + 1 < 64) load4(bbA, bptr(nt + 1), 0);   // first half of next
        mfmaH(acc, bbB, 4);

        // bins: 8 elements; per element fmed3 + cvt + addr + ds_add(1u)
        #pragma unroll
        for (int s = 0; s < 2; ++s)
            #pragma unroll
            for (int reg = 0; reg < 4; ++reg) {
                int b = (int)__builtin_amdgcn_fmed3f(acc[s][reg], 0.0f, 511.0f);
                atomicAdd(&Hrow[s][b], 1u);
            }
    }
    __syncthreads();   // all waves' atomics visible

    // epilogue, in-register per wave: rows 8w .. 8w+7 (u32, contiguous reads)
    const float binw = RANGE / (float)BINS;
    #pragma unroll
    for (int rr = 0; rr < 8; ++rr) {
        const int r = wave * 8 + rr;
        const unsigned int* H = &hist[r * BINS];
        // lane L holds bins 8L .. 8L+7
        uint4 wa = *(const uint4*)(H + 8 * lane);
        uint4 wb = *(const uint4*)(H + 8 * lane + 4);
        int cnt[8] = {(int)wa.x, (int)wa.y, (int)wa.z, (int)wa.w,
                      (int)wb.x, (int)wb.y, (int)wb.z, (int)wb.w};
        int local = 0;
        #pragma unroll
        for (int u = 0; u < 8; ++u) local += cnt[u];
        // suffix-sum over lanes
        int suf = local;
        #pragma unroll
        for (int o2 = 1; o2 < 64; o2 <<= 1) {
            int o = __shfl_down(suf, o2, 64);
            if (lane + o2 < 64) suf += o;
        }
        int run = suf - local;
        int s[8];                       // s[u] = S[8*lane+u] = #values >= edge
        #pragma unroll
        for (int u = 7; u >= 0; --u) { run += cnt[u]; s[u] = run; }

        // answer 256 queries for this row: lane handles i = qq*64 + lane
        #pragma unroll
        for (int qq = 0; qq < 4; ++qq) {
            int i = qq * 64 + lane;
            float rv = 1.0f + (float)i * (4094.0f / 255.0f);
            int k = (int)rintf(rv) + 1;   // k-th largest, k in [2, 4096]
            int Lo = 0;
            #pragma unroll
            for (int st = 32; st >= 1; st >>= 1) {
                int cand = Lo + st;       // always <= 63
                int v = __shfl(s[0], cand, 64);
                if (v >= k) Lo = cand;
            }
            int j8 = 0;
            #pragma unroll
            for (int u = 0; u < 8; ++u) {
                int v = __shfl(s[u], Lo, 64);
                j8 += (v >= k) ? 1 : 0;
            }
            int j = 8 * Lo + j8 - 1;
            out[(size_t)(batch * 4096 + m0 + r) * 256 + i] = LO + ((float)j + 0.5f) * binw;
        }
    }
}

extern "C" void kernel_launch(void* const* d_in, const int* in_sizes, int n_in,
                              void* d_out, int out_size, void* d_ws, size_t ws_size,
                              hipStream_t stream) {
    static int attr_set = 0;
    if (!attr_set) {   // one-time, host-side, not a stream op (capture-safe)
        (void)hipFuncSetAttribute((const void*)scpp_kernel,
                                  hipFuncAttributeMaxDynamicSharedMemorySize, 131072);
        attr_set = 1;
    }
    const float* x = (const float*)d_in[0];
    float* out = (float*)d_out;
    short* xb = (short*)d_ws;                              // 16 MB blocked bf16
    hipLaunchKernelGGL(cvt_kernel, dim3(4096), dim3(256), 0, stream, x, xb);
    hipLaunchKernelGGL(scpp_kernel, dim3(512), dim3(THREADS), 131072, stream, xb, out);
}

// Round 17
// 172.881 us; speedup vs baseline: 1.0297x; 1.0110x over previous
//
#include <hip/hip_runtime.h>

#define THREADS 512            // 8 waves/block; 1 block/CU
#define ROWS    128            // rows per block
#define BINS    512
#define WORDS   256            // u16-packed: 2 bins per u32 word (conflict fix)
#define LO      (-0.6f)
#define RANGE   (1.3f)

typedef short bf16x8 __attribute__((ext_vector_type(8)));
typedef float f32x4  __attribute__((ext_vector_type(4)));

// fp32 -> bf16 with round-to-nearest-even
__device__ __forceinline__ short f2bf(float f) {
    unsigned int u = __builtin_bit_cast(unsigned int, f);
    u = (u + 0x7FFFu + ((u >> 16) & 1u)) >> 16;
    return (short)u;
}

// cvt: fp32 -> bf16 into the FRAGMENT-BLOCKED layout (R13) so every MFMA
// operand load in scpp is one fully-coalesced dwordx4 at base+lane*16B.
__global__ __launch_bounds__(256)
void cvt_kernel(const float* __restrict__ X, short* __restrict__ Xb) {
    int i    = blockIdx.x * 256 + threadIdx.x;   // 0 .. 2^20-1
    int lane = i & 63;
    int ks   = (i >> 6) & 7;
    int g    = (i >> 9) & 255;
    int b    = i >> 17;
    int ln   = lane & 15, kq = lane >> 4;
    const float* src = X + ((size_t)(b * 4096 + g * 16 + ln) * 256 + ks * 32 + kq * 8);
    float4 v0 = ((const float4*)src)[0];
    float4 v1 = ((const float4*)src)[1];
    bf16x8 o;
    o[0] = f2bf(v0.x); o[1] = f2bf(v0.y); o[2] = f2bf(v0.z); o[3] = f2bf(v0.w);
    o[4] = f2bf(v1.x); o[5] = f2bf(v1.y); o[6] = f2bf(v1.z); o[7] = f2bf(v1.w);
    *(bf16x8*)(Xb + ((size_t)b << 20) + g * 4096 + ks * 512 + lane * 8) = o;
}

// R17 = R14 (best, 102.9us) with u16 histogram packing instead of u8.
// Evidence: R16 showed DS conflicts couple to runtime (+1.8e6 conflicts ->
// +2us) while VALU work does not (-40k cy -> null). u8's 4-bins/word makes
// Gaussian same-row lanes collide on one word (sigma ~6 words); u16 halves
// same-word collision rate and doubles word spread. XOR row-swizzle kept
// (masks 9*ln mod 32 are distinct over ln=0..15 -> 16-bank row spread).
__global__ __launch_bounds__(THREADS, 2)   // 8 waves = 2/SIMD; cap 256
void scpp_kernel(const short* __restrict__ X, float* __restrict__ out) {
    extern __shared__ unsigned int hist[];   // 128 rows x 256 words = 128 KB

    const int t    = threadIdx.x;
    const int wave = t >> 6;           // 0..7
    const int lane = t & 63;
    const int ln   = lane & 15;
    const int h    = wave >> 2;        // row-half: rows m0 + h*64 .. +63
    const int cg   = wave & 3;         // col-group: cols nt*64 + cg*16 .. +15
    const int bid  = blockIdx.x;       // 0..255 -> 1 block/CU, zero tail
    const int batch = bid & 7;         // XCD-batch pinning
    const int m0    = (bid >> 3) * ROWS;
    const short* Xb = X + ((size_t)batch << 20);

    // zero histograms: 32768 words / 512 threads
    #pragma unroll
    for (int i = 0; i < (ROWS * WORDS) / THREADS; ++i)
        hist[t + THREADS * i] = 0u;

    // A fragments: 4 strips of 16 rows; coalesced fragment loads; AGPR-resident.
    bf16x8 af[4][8];
    {
        #pragma unroll
        for (int s = 0; s < 4; ++s) {
            const short* ap = Xb + (size_t)((m0 >> 4) + h * 4 + s) * 4096 + lane * 8;
            #pragma unroll
            for (int ks = 0; ks < 8; ++ks)
                af[s][ks] = *(const bf16x8*)(ap + ks * 512);
        }
        #pragma unroll
        for (int s = 0; s < 4; ++s)
            #pragma unroll
            for (int ks = 0; ks < 8; ++ks)
                asm volatile("" : "+v"(af[s][ks]));   // opaque: blocks remat
    }
    __syncthreads();   // hist zeros visible before atomics

    // bin transform: b = (v/256 - LO) * BINS/RANGE == v*scale + off
    const float scale = ((float)BINS / RANGE) / 256.0f;
    const float off   = -LO * ((float)BINS / RANGE);

    // loop-invariant per-strip histogram row pointer + bank swizzle
    unsigned int* Hrow[4];
    unsigned      swzr[4];
    #pragma unroll
    for (int s = 0; s < 4; ++s) {
        int row = h * 64 + s * 16 + ln;
        Hrow[s] = &hist[row * WORDS];
        swzr[s] = (unsigned)((row * 9) & 31);
    }

    // B fragment base for tile nt (coalesced: base + lane*16B)
    auto bptr = [&](int nt) {
        return Xb + (size_t)(nt * 4 + cg) * 4096 + lane * 8;
    };
    auto load4 = [&](bf16x8* d, const short* p, int ks0) {
        #pragma unroll
        for (int j = 0; j < 4; ++j)
            d[j] = *(const bf16x8*)(p + (ks0 + j) * 512);
    };
    auto mfmaH = [&](f32x4* acc, const bf16x8* bx, int ks0) {
        __builtin_amdgcn_s_setprio(1);
        #pragma unroll
        for (int j = 0; j < 4; ++j)
            #pragma unroll
            for (int s = 0; s < 4; ++s)   // swapped: bb as A, af as B -> D^T
                acc[s] = __builtin_amdgcn_mfma_f32_16x16x32_bf16(bx[j], af[s][ks0 + j], acc[s], 0, 0, 0);
        __builtin_amdgcn_s_setprio(0);
    };
    auto zero4 = [&](f32x4* acc) {
        #pragma unroll
        for (int s = 0; s < 4; ++s) acc[s] = f32x4{0.f, 0.f, 0.f, 0.f};
    };
    // bin 2 strips (8 elements) of a finished accumulator; u16 packing
    auto binsH = [&](const f32x4* acc, int sbase) {
        #pragma unroll
        for (int s2 = 0; s2 < 2; ++s2) {
            const int s = sbase + s2;
            #pragma unroll
            for (int reg = 0; reg < 4; ++reg) {
                int b  = (int)__builtin_amdgcn_fmed3f(
                             acc[s][reg] * scale + off, 0.0f, 511.0f);
                int pw = (b >> 1) ^ swzr[s];
                atomicAdd(&Hrow[s][pw], 1u << ((b & 1) * 16));
            }
        }
    };

    // K-loop: register ping-pong + deferred bins (R14 structure, proven).
    f32x4 accE[4], accO[4];
    bf16x8 bA[4], bB[4], bA2[4], bB2[4];

    load4(bA, bptr(0), 0); load4(bB, bptr(0), 4);
    zero4(accE);
    mfmaH(accE, bA, 0);  load4(bA2, bptr(1), 0);
    mfmaH(accE, bB, 4);  load4(bB2, bptr(1), 4);

    for (int nt = 1; nt < 63; nt += 2) {
        zero4(accO);                                     // tile nt -> accO; bins nt-1
        mfmaH(accO, bA2, 0);  load4(bA, bptr(nt + 1), 0);  binsH(accE, 0);
        mfmaH(accO, bB2, 4);  load4(bB, bptr(nt + 1), 4);  binsH(accE, 2);
        zero4(accE);                                     // tile nt+1 -> accE; bins nt
        mfmaH(accE, bA, 0);   load4(bA2, bptr(nt + 2), 0); binsH(accO, 0);
        mfmaH(accE, bB, 4);   load4(bB2, bptr(nt + 2), 4); binsH(accO, 2);
    }
    // tail: bA2/bB2 hold tile 63; accE holds tile 62 (unbinned)
    zero4(accO);
    mfmaH(accO, bA2, 0);  binsH(accE, 0);
    mfmaH(accO, bB2, 4);  binsH(accE, 2);
    binsH(accO, 0);
    binsH(accO, 2);
    __syncthreads();   // all waves' atomics visible

    // epilogue, in-register per wave: rows 16w .. 16w+15 (u16 unpack)
    const float binw = RANGE / (float)BINS;
    #pragma unroll
    for (int rr = 0; rr < 16; ++rr) {
        const int r = wave * 16 + rr;
        const unsigned int msk = (unsigned int)(r * 9) & 31u;
        const unsigned int* H = &hist[r * WORDS];
        // lane L holds logical words 4L..4L+3 = bins 8L..8L+7 (un-swizzle)
        int cnt[8];
        #pragma unroll
        for (int i2 = 0; i2 < 4; ++i2) {
            unsigned int wd = H[(unsigned int)(4 * lane + i2) ^ msk];
            cnt[2 * i2]     = (int)(wd & 0xFFFFu);
            cnt[2 * i2 + 1] = (int)(wd >> 16);
        }
        int local = 0;
        #pragma unroll
        for (int u = 0; u < 8; ++u) local += cnt[u];
        // suffix-sum over lanes
        int suf = local;
        #pragma unroll
        for (int o2 = 1; o2 < 64; o2 <<= 1) {
            int o = __shfl_down(suf, o2, 64);
            if (lane + o2 < 64) suf += o;
        }
        int run = suf - local;
        int s[8];                       // s[u] = S[8*lane+u] = #values >= edge
        #pragma unroll
        for (int u = 7; u >= 0; --u) { run += cnt[u]; s[u] = run; }

        // answer 256 queries for this row: lane handles i = qq*64 + lane
        #pragma unroll
        for (int qq = 0; qq < 4; ++qq) {
            int i = qq * 64 + lane;
            float rv = 1.0f + (float)i * (4094.0f / 255.0f);
            int k = (int)rintf(rv) + 1;   // k-th largest, k in [2, 4096]
            int Lo = 0;
            #pragma unroll
            for (int st = 32; st >= 1; st >>= 1) {
                int cand = Lo + st;       // always <= 63
                int v = __shfl(s[0], cand, 64);
                if (v >= k) Lo = cand;
            }
            int j8 = 0;
            #pragma unroll
            for (int u = 0; u < 8; ++u) {
                int v = __shfl(s[u], Lo, 64);
                j8 += (v >= k) ? 1 : 0;
            }
            int j = 8 * Lo + j8 - 1;
            out[(size_t)(batch * 4096 + m0 + r) * 256 + i] = LO + ((float)j + 0.5f) * binw;
        }
    }
}

extern "C" void kernel_launch(void* const* d_in, const int* in_sizes, int n_in,
                              void* d_out, int out_size, void* d_ws, size_t ws_size,
                              hipStream_t stream) {
    static int attr_set = 0;
    if (!attr_set) {   // one-time, host-side, not a stream op (capture-safe)
        (void)hipFuncSetAttribute((const void*)scpp_kernel,
                                  hipFuncAttributeMaxDynamicSharedMemorySize, 131072);
        attr_set = 1;
    }
    const float* x = (const float*)d_in[0];
    float* out = (float*)d_out;
    short* xb = (short*)d_ws;                              // 16 MB blocked bf16
    hipLaunchKernelGGL(cvt_kernel, dim3(4096), dim3(256), 0, stream, x, xb);
    hipLaunchKernelGGL(scpp_kernel, dim3(256), dim3(THREADS), 131072, stream, xb, out);
}